// Round 13
// baseline (257.553 us; speedup 1.0000x reference)
//
#include <hip/hip_runtime.h>

// LDPC sum-product BP decode, (3,6)-regular, N=8192, R=4096, B=1024, 10 iters.
//
// R6: persistent-LDS — one workgroup per batch element, all state in LDS.
// R7: 1024 threads, per-thread check ownership, prev state in registers.
// R8 LESSON: never subtract near-equal large products; clamp before ratios.
// R10: exp-domain state (E_s = e^tot, q_s = e^c2v): zero exp/log in hot loop.
//      Kernel sits at the LDS floor: ~11K cyc/block-iter = ~6.9K issue
//      (72 wave-instrs) + ~3.8K bank-conflict (48 graph-random b32 ops).
// R11 LESSON: ballot-scan build = 4096 x 24576 scan = ~150us. Reverted.
// R13: SINGLE dispatch. Table built per-block in LDS: scatter via LDS
//      atomics into the q_s region (table consumed into registers before
//      q_s is first written), counters in the E_s region (overwritten by
//      init after a barrier). Rows sorted ascending -> table and output
//      BIT-IDENTICAL to R12 (absmax 0.03125); deterministic -> tripwire-OK.
//
// All ranges audited finite: E in [2e-15, 5e14], q in [5e-4, 1999]. No NaN.

#define N_  8192
#define R_  4096
#define DV_ 3
#define DC_ 6
#define E_  (N_ * DV_)
#define B_  1024
#define ITERS_ 10

#define THREADS_ 1024
#define CPT_ (R_ / THREADS_)   // 4 checks per thread
#define VPT_ (N_ / THREADS_)   // 8 variables per thread
#define EPT_ (E_ / THREADS_)   // 24 edges per thread (table build)

#define LOG2E_ 1.442695041f
#define LN2_   0.69314718f

// Persistent exp-domain BP: block b decodes batch element b entirely in LDS.
// E_s[v] = e^{tot[v]}, q_s[e] = e^{c2v[e]}, messages var-major (e = 3v+j).
__global__ __launch_bounds__(THREADS_) void persistent_kernel(
    const float* __restrict__ recv, const int* __restrict__ edge_check,
    float* __restrict__ out) {
  __shared__ float q_s[E_];  // 96 KB; during init: check->edge table (int)
  __shared__ float E_s[N_];  // 32 KB; during init: first 16 KB = counters
  const int b = blockIdx.x;
  const int tid = threadIdx.x;
  const float* r = recv + (size_t)b * N_;

  // ---- per-block table build (aliased into q_s / E_s regions) ----
  int* table = (int*)q_s;       // R_*DC_ ints = 96 KB
  int* counters = (int*)E_s;    // R_ ints = 16 KB
#pragma unroll
  for (int k = 0; k < R_ / THREADS_; k++) counters[tid + k * THREADS_] = 0;
  __syncthreads();
#pragma unroll
  for (int k = 0; k < EPT_; k++) {
    int e = tid + k * THREADS_;          // coalesced; same 96 KB all blocks -> L2
    int rr = edge_check[e];
    int slot = atomicAdd(&counters[rr], 1);  // LDS atomic, slots 0..5
    table[rr * DC_ + slot] = e;
  }
  __syncthreads();

  // This thread's 4 check rows -> registers; sort each row ascending
  // (12-comparator optimal network) so the table is deterministic and
  // bit-identical to the sorted builds of R3..R12.
  int eidx[CPT_][DC_];
  int vidx[CPT_][DC_];
#pragma unroll
  for (int c = 0; c < CPT_; c++) {
    int rr = c * THREADS_ + tid;
    int e0 = table[rr * DC_ + 0], e1 = table[rr * DC_ + 1];
    int e2 = table[rr * DC_ + 2], e3 = table[rr * DC_ + 3];
    int e4 = table[rr * DC_ + 4], e5 = table[rr * DC_ + 5];
#define CSWAP(a, b) { int lo = min(a, b), hi = max(a, b); a = lo; b = hi; }
    CSWAP(e0, e5) CSWAP(e1, e3) CSWAP(e2, e4)
    CSWAP(e1, e2) CSWAP(e3, e4)
    CSWAP(e0, e3) CSWAP(e2, e5)
    CSWAP(e0, e1) CSWAP(e2, e3) CSWAP(e4, e5)
    CSWAP(e1, e2) CSWAP(e3, e4)
#undef CSWAP
    eidx[c][0] = e0; eidx[c][1] = e1; eidx[c][2] = e2;
    eidx[c][3] = e3; eidx[c][4] = e4; eidx[c][5] = e5;
#pragma unroll
    for (int i = 0; i < DC_; i++)
      vidx[c][i] = (int)((unsigned)eidx[c][i] / 3u);  // edge_var[e] == e/3
  }
  __syncthreads();  // all table reads done; q_s/E_s regions may be reused

  // (1-y, 1+y) of own previous c2v output; c2v=0 <=> y=0 <=> (1,1).
  float hn[CPT_][DC_], hd[CPT_][DC_];
#pragma unroll
  for (int c = 0; c < CPT_; c++)
#pragma unroll
    for (int i = 0; i < DC_; i++) { hn[c][i] = 1.0f; hd[c][i] = 1.0f; }

  // e^{llr} per owned var (llr = 2*recv); the only exps in the kernel.
  // Overwrites the counters region — safe after the barrier above.
  float e_llr[VPT_];
#pragma unroll
  for (int k = 0; k < VPT_; k++) {
    float llr = 2.0f * r[tid + k * THREADS_];
    e_llr[k] = __builtin_amdgcn_exp2f(llr * LOG2E_);
    E_s[tid + k * THREADS_] = e_llr[k];
  }
  __syncthreads();

  for (int iter = 0; iter < ITERS_; iter++) {
    // ---- check phase: no exp/log. t = tanh((tot - c2v_prev)/2) computed as
    // (E*hn - hd) / (E*hn + hd), since e^{tot-c2v} = E * (1-y)/(1+y).
    // First iteration's writes cover every q_s entry (table fully clobbered,
    // already in registers). ----
#pragma unroll
    for (int c = 0; c < CPT_; c++) {
      float t[DC_];
#pragma unroll
      for (int i = 0; i < DC_; i++) {
        float A = E_s[vidx[c][i]] * hn[c][i];
        float num = A - hd[c][i];
        float den = A + hd[c][i];  // strictly positive
        t[i] = num * __builtin_amdgcn_rcpf(den);
      }
      // leave-one-out products via prefix/suffix (division-free, |t|<=1+eps)
      float loo[DC_];
      float run = 1.0f;
#pragma unroll
      for (int i = 0; i < DC_; i++) { loo[i] = run; run *= t[i]; }
      run = 1.0f;
#pragma unroll
      for (int i = DC_ - 1; i >= 0; i--) { loo[i] *= run; run *= t[i]; }
#pragma unroll
      for (int i = 0; i < DC_; i++) {
        // clamp FIRST (reference clip semantics; keeps qd,qn >= 0.001 > 0)
        float y = loo[i];
        y = fminf(fmaxf(y, -0.999f), 0.999f);
        float qd = 1.0f - y;  // = hn_next (e^{-c2v} = qd/qn)
        float qn = 1.0f + y;  // = hd_next
        q_s[eidx[c][i]] = qn * __builtin_amdgcn_rcpf(qd);  // e^{c2v}
        hn[c][i] = qd;
        hd[c][i] = qn;
      }
    }
    __syncthreads();
    // ---- variable phase: E = e^{llr} * q0*q1*q2; q0,q1 paired into one
    // ds_read2_b32 (4B-aligned float2), q2 single. ----
#pragma unroll
    for (int k = 0; k < VPT_; k++) {
      int v = tid + k * THREADS_;
      float2 q01;
      __builtin_memcpy(&q01, &q_s[3 * v], sizeof(float2));
      float q2 = q_s[3 * v + 2];
      E_s[v] = ((e_llr[k] * q01.x) * q01.y) * q2;
    }
    __syncthreads();
  }

  // ---- output: LLR = ln(E); bits = (LLR < 0); [B,N] layout ----
  const size_t BN = (size_t)B_ * N_;
#pragma unroll
  for (int k = 0; k < VPT_; k++) {
    int n = tid + k * THREADS_;
    float val = LN2_ * __builtin_amdgcn_logf(E_s[n]);  // E in [2e-15,5e14]
    out[(size_t)b * N_ + n] = val;
    out[BN + (size_t)b * N_ + n] = (val < 0.0f) ? 1.0f : 0.0f;
  }
}

extern "C" void kernel_launch(void* const* d_in, const int* in_sizes, int n_in,
                              void* d_out, int out_size, void* d_ws,
                              size_t ws_size, hipStream_t stream) {
  const float* recv = (const float*)d_in[0];     // [B, N]
  const int* edge_check = (const int*)d_in[2];   // [E]
  float* out = (float*)d_out;
  persistent_kernel<<<B_, THREADS_, 0, stream>>>(recv, edge_check, out);
}

// Round 14
// 241.111 us; speedup vs baseline: 1.0682x; 1.0682x over previous
//
#include <hip/hip_runtime.h>

// LDPC sum-product BP decode, (3,6)-regular, N=8192, R=4096, B=1024, 10 iters.
//
// R6: persistent-LDS — one workgroup per batch element, all state in LDS.
// R7: 1024 threads, per-thread check ownership, prev state in registers.
// R8 LESSON: never subtract near-equal large products; clamp before ratios.
// R10: exp-domain state (E_s = e^tot, q_s = e^c2v): zero exp/log in hot loop;
//      kernel sits at the LDS-pipe floor (~11K cyc/block-iter: ~1150 LDS
//      wave-instrs issue+word cost + ~3.8K conflict cycles on the 48
//      graph-random b32 ops/thread-iter; VALU 55% hides underneath).
// R11 LESSON: ballot-scan build = 4096 x 24576 scan = ~150us. Reverted.
// R12 (FINAL): two dispatches, zero memsets:
//      (a) atomic build with MOD-6 slots: the 6 atomicAdd returns per check
//          are consecutive ints -> ret%6 is a permutation of 0..5 for ANY
//          initial counter value (poison-proof, no memset needed);
//      (b) per-row ascending sort in persistent init (12-comparator network)
//          -> deterministic table, bit-stable output (absmax 0.03125).
// R13 LESSON: fusing the build into the persistent kernel replicates it
//      1024x (+12us kernel); harness overhead (~58us) is dispatch-count
//      invariant. Two dispatches is optimal. This file = R12 verbatim.
//
// All ranges audited finite: E in [2e-15, 5e14], q in [5e-4, 1999]. No NaN.

#define N_  8192
#define R_  4096
#define DV_ 3
#define DC_ 6
#define E_  (N_ * DV_)
#define B_  1024
#define ITERS_ 10

#define THREADS_ 1024
#define CPT_ (R_ / THREADS_)   // 4 checks per thread
#define VPT_ (N_ / THREADS_)   // 8 variables per thread

#define LOG2E_ 1.442695041f
#define LN2_   0.69314718f

// Scatter edges into per-check rows. counters is UNINITIALIZED scratch: the
// 6 returns per check are consecutive, so ret%6 covers slots 0..5 exactly.
// Row content order is nondeterministic; persistent_kernel sorts each row.
__global__ __launch_bounds__(256) void build_edges_kernel(
    const int* __restrict__ edge_check, unsigned int* __restrict__ counters,
    int* __restrict__ check_edges) {
  int e = blockIdx.x * 256 + threadIdx.x;
  if (e < E_) {
    int r = edge_check[e];
    unsigned int ret = atomicAdd(&counters[r], 1u);
    check_edges[r * DC_ + (ret % 6u)] = e;
  }
}

// Persistent exp-domain BP: block b decodes batch element b entirely in LDS.
// E_s[v] = e^{tot[v]}, q_s[e] = e^{c2v[e]}.
__global__ __launch_bounds__(THREADS_) void persistent_kernel(
    const float* __restrict__ recv, const int* __restrict__ check_edges,
    float* __restrict__ out) {
  __shared__ float q_s[E_];  // 96 KB, e^{c2v}, var-major (e = 3v+j)
  __shared__ float E_s[N_];  // 32 KB, e^{tot}
  const int b = blockIdx.x;
  const int tid = threadIdx.x;
  const float* r = recv + (size_t)b * N_;

  // This thread's 4 check rows -> registers; sort each row ascending
  // (12-comparator optimal network) so the table is deterministic and
  // bit-identical to the sorted-atomic builds of R3..R10.
  int eidx[CPT_][DC_];
  int vidx[CPT_][DC_];
#pragma unroll
  for (int c = 0; c < CPT_; c++) {
    int rr = c * THREADS_ + tid;
    int e0 = check_edges[rr * DC_ + 0], e1 = check_edges[rr * DC_ + 1];
    int e2 = check_edges[rr * DC_ + 2], e3 = check_edges[rr * DC_ + 3];
    int e4 = check_edges[rr * DC_ + 4], e5 = check_edges[rr * DC_ + 5];
#define CSWAP(a, b) { int lo = min(a, b), hi = max(a, b); a = lo; b = hi; }
    CSWAP(e0, e5) CSWAP(e1, e3) CSWAP(e2, e4)
    CSWAP(e1, e2) CSWAP(e3, e4)
    CSWAP(e0, e3) CSWAP(e2, e5)
    CSWAP(e0, e1) CSWAP(e2, e3) CSWAP(e4, e5)
    CSWAP(e1, e2) CSWAP(e3, e4)
#undef CSWAP
    eidx[c][0] = e0; eidx[c][1] = e1; eidx[c][2] = e2;
    eidx[c][3] = e3; eidx[c][4] = e4; eidx[c][5] = e5;
#pragma unroll
    for (int i = 0; i < DC_; i++)
      vidx[c][i] = (int)((unsigned)eidx[c][i] / 3u);  // edge_var[e] == e/3
  }
  // (1-y, 1+y) of own previous c2v output; c2v=0 <=> y=0 <=> (1,1).
  float hn[CPT_][DC_], hd[CPT_][DC_];
#pragma unroll
  for (int c = 0; c < CPT_; c++)
#pragma unroll
    for (int i = 0; i < DC_; i++) { hn[c][i] = 1.0f; hd[c][i] = 1.0f; }

  // e^{llr} per owned var (llr = 2*recv); the only exps in the kernel.
  float e_llr[VPT_];
#pragma unroll
  for (int k = 0; k < VPT_; k++) {
    float llr = 2.0f * r[tid + k * THREADS_];
    e_llr[k] = __builtin_amdgcn_exp2f(llr * LOG2E_);
    E_s[tid + k * THREADS_] = e_llr[k];
  }
  __syncthreads();

  for (int iter = 0; iter < ITERS_; iter++) {
    // ---- check phase: no exp/log. t = tanh((tot - c2v_prev)/2) computed as
    // (E*hn - hd) / (E*hn + hd), since e^{tot-c2v} = E * (1-y)/(1+y). ----
#pragma unroll
    for (int c = 0; c < CPT_; c++) {
      float t[DC_];
#pragma unroll
      for (int i = 0; i < DC_; i++) {
        float A = E_s[vidx[c][i]] * hn[c][i];
        float num = A - hd[c][i];
        float den = A + hd[c][i];  // strictly positive
        t[i] = num * __builtin_amdgcn_rcpf(den);
      }
      // leave-one-out products via prefix/suffix (division-free, |t|<=1+eps)
      float loo[DC_];
      float run = 1.0f;
#pragma unroll
      for (int i = 0; i < DC_; i++) { loo[i] = run; run *= t[i]; }
      run = 1.0f;
#pragma unroll
      for (int i = DC_ - 1; i >= 0; i--) { loo[i] *= run; run *= t[i]; }
#pragma unroll
      for (int i = 0; i < DC_; i++) {
        // clamp FIRST (reference clip semantics; keeps qd,qn >= 0.001 > 0)
        float y = loo[i];
        y = fminf(fmaxf(y, -0.999f), 0.999f);
        float qd = 1.0f - y;  // = hn_next (e^{-c2v} = qd/qn)
        float qn = 1.0f + y;  // = hd_next
        q_s[eidx[c][i]] = qn * __builtin_amdgcn_rcpf(qd);  // e^{c2v}
        hn[c][i] = qd;
        hd[c][i] = qn;
      }
    }
    __syncthreads();
    // ---- variable phase: E = e^{llr} * q0*q1*q2; q0,q1 paired into one
    // ds_read2_b32 (4B-aligned float2), q2 single. ----
#pragma unroll
    for (int k = 0; k < VPT_; k++) {
      int v = tid + k * THREADS_;
      float2 q01;
      __builtin_memcpy(&q01, &q_s[3 * v], sizeof(float2));
      float q2 = q_s[3 * v + 2];
      E_s[v] = ((e_llr[k] * q01.x) * q01.y) * q2;
    }
    __syncthreads();
  }

  // ---- output: LLR = ln(E); bits = (LLR < 0); [B,N] layout ----
  const size_t BN = (size_t)B_ * N_;
#pragma unroll
  for (int k = 0; k < VPT_; k++) {
    int n = tid + k * THREADS_;
    float val = LN2_ * __builtin_amdgcn_logf(E_s[n]);  // E in [2e-15,5e14]
    out[(size_t)b * N_ + n] = val;
    out[BN + (size_t)b * N_ + n] = (val < 0.0f) ? 1.0f : 0.0f;
  }
}

extern "C" void kernel_launch(void* const* d_in, const int* in_sizes, int n_in,
                              void* d_out, int out_size, void* d_ws,
                              size_t ws_size, hipStream_t stream) {
  const float* recv = (const float*)d_in[0];     // [B, N]
  const int* edge_check = (const int*)d_in[2];   // [E]
  float* out = (float*)d_out;

  char* ws = (char*)d_ws;
  unsigned int* counters = (unsigned int*)ws;           // 16 KB, UNINITIALIZED
  int* check_edges = (int*)(ws + (size_t)R_ * sizeof(unsigned int));  // 96 KB

  build_edges_kernel<<<(E_ + 255) / 256, 256, 0, stream>>>(edge_check, counters,
                                                           check_edges);
  persistent_kernel<<<B_, THREADS_, 0, stream>>>(recv, check_edges, out);
}